// Round 5
// baseline (557.420 us; speedup 1.0000x reference)
//
#include <hip/hip_runtime.h>

typedef _Float16 h2_t __attribute__((ext_vector_type(2)));
typedef _Float16 f16x4v __attribute__((ext_vector_type(4)));
typedef _Float16 f16x8 __attribute__((ext_vector_type(8)));
typedef float f32x4 __attribute__((ext_vector_type(4)));

struct F8pair { f16x4v lo, hi; };
static __device__ __forceinline__ f16x8 ldfrag(const _Float16* p) {
    F8pair r;
    r.lo = *(const f16x4v*)p;
    r.hi = *(const f16x4v*)(p + 4);
    return __builtin_bit_cast(f16x8, r);
}

static __device__ __forceinline__ float fdot2f(unsigned int a, unsigned int b, float c) {
#if __has_builtin(__builtin_amdgcn_fdot2)
    return __builtin_amdgcn_fdot2(__builtin_bit_cast(h2_t, a), __builtin_bit_cast(h2_t, b), c, false);
#else
    float d;
    asm volatile("v_dot2_f32_f16 %0, %1, %2, %3" : "=v"(d) : "v"(a), "v"(b), "v"(c));
    return d;
#endif
}

static __device__ __forceinline__ unsigned int packh2(float a, float b) {
    h2_t h;
    h.x = (_Float16)a;
    h.y = (_Float16)b;
    return __builtin_bit_cast(unsigned int, h);
}

static __device__ __forceinline__ unsigned int pkrtz(float a, float b) {
    return __builtin_bit_cast(unsigned int, __builtin_amdgcn_cvt_pkrtz(a, b));
}

// ---------------- precompute: folded weight products ----------------
// PsW = W_src@Wa1 [128,64] f32, PdW = W_dst@Wa1 [128,64] f32 (for k_node)
// Mpk/Wp2pk/Wa2pk: packed fp16 pairs (fallback k_agg)
// Wcat: fp16 [320][68]: rows 0-63  Mt[l][h]   = M[h][l], M = Wp2@Wa1
//                       rows 64-191 Wp2t[c][h] = Wp2[h][c]
//                       rows 192-319 Wa2t[c][l] = Wa2[l][c]
// bias2[l] = ba1[l] + sum_c bp2[c]*Wa1[c][l]
__global__ void k_pre(const float* __restrict__ W_src, const float* __restrict__ W_dst,
                      const float* __restrict__ Wa1, const float* __restrict__ ba1,
                      const float* __restrict__ Wp2, const float* __restrict__ bp2,
                      const float* __restrict__ Wa2,
                      float* __restrict__ PsW, float* __restrict__ PdW,
                      unsigned int* __restrict__ Mpk, unsigned int* __restrict__ Wp2pk,
                      unsigned int* __restrict__ Wa2pk, float* __restrict__ bias2,
                      _Float16* __restrict__ Wcat)
{
    int idx = blockIdx.x * 256 + threadIdx.x;
    if (idx < 8192) {
        int k = idx >> 6, l = idx & 63;
        float a = 0.f;
        for (int c = 0; c < 128; ++c) a = fmaf(W_src[k*128+c], Wa1[c*64+l], a);
        PsW[idx] = a;
    } else if (idx < 16384) {
        int j = idx - 8192; int k = j >> 6, l = j & 63;
        float a = 0.f;
        for (int c = 0; c < 128; ++c) a = fmaf(W_dst[k*128+c], Wa1[c*64+l], a);
        PdW[j] = a;
    } else if (idx < 18432) {
        int j = idx - 16384; int t = j >> 6, l = j & 63;
        float m0 = 0.f, m1 = 0.f;
        for (int c = 0; c < 128; ++c) {
            m0 = fmaf(Wp2[(2*t)*128+c],   Wa1[c*64+l], m0);
            m1 = fmaf(Wp2[(2*t+1)*128+c], Wa1[c*64+l], m1);
        }
        Mpk[j] = packh2(m0, m1);
    } else if (idx < 22528) {
        int j = idx - 18432; int t = j >> 7, c = j & 127;
        Wp2pk[j] = packh2(Wp2[(2*t)*128+c], Wp2[(2*t+1)*128+c]);
    } else if (idx < 26624) {
        int j = idx - 22528; int t = j >> 7, c = j & 127;
        Wa2pk[j] = packh2(Wa2[(2*t)*128+c], Wa2[(2*t+1)*128+c]);
    } else if (idx < 26688) {
        int l = idx - 26624;
        float a = ba1[l];
        for (int c = 0; c < 128; ++c) a = fmaf(bp2[c], Wa1[c*64+l], a);
        bias2[l] = a;
    } else if (idx < 26688 + 320*68) {
        int j = idx - 26688;
        int row = j / 68, k = j % 68;
        float val = 0.f;
        if (k < 64) {
            if (row < 64) {            // Mt[l=row][h=k] = M[k][row]
                float a = 0.f;
                for (int c = 0; c < 128; ++c) a = fmaf(Wp2[k*128+c], Wa1[c*64+row], a);
                val = a;
            } else if (row < 192) {    // Wp2t[c][h] = Wp2[k][c]
                val = Wp2[k*128 + (row - 64)];
            } else {                   // Wa2t[c][l] = Wa2[k][c]
                val = Wa2[k*128 + (row - 192)];
            }
        }
        Wcat[j] = (_Float16)val;
    }
}

// ---------------- CSR build ----------------
__global__ void k_zero(int* __restrict__ p, int n) {
    int i = blockIdx.x * 256 + threadIdx.x;
    if (i < n) p[i] = 0;
}

__global__ void k_count(const int* __restrict__ ei, int E, int N, int* __restrict__ cnt) {
    int i = blockIdx.x * 256 + threadIdx.x;
    int T = E + N;
    if (i >= T) return;
    int dst = (i < E) ? ei[E + i] : (i - E);
    atomicAdd(&cnt[dst], 1);
}

__global__ void k_pos4(const float* __restrict__ pos, float4* __restrict__ pos4, int N) {
    int i = blockIdx.x * 256 + threadIdx.x;
    if (i < N) pos4[i] = make_float4(pos[3*i], pos[3*i+1], pos[3*i+2], 0.f);
}

__global__ __launch_bounds__(1024) void k_scan1(int* __restrict__ cnt, int* __restrict__ bsum, int N) {
    __shared__ int sc[1024];
    int t = threadIdx.x;
    int i = blockIdx.x * 1024 + t;
    int val = (i < N) ? cnt[i] : 0;
    sc[t] = val;
    __syncthreads();
    for (int off = 1; off < 1024; off <<= 1) {
        int tmp = (t >= off) ? sc[t - off] : 0;
        __syncthreads();
        sc[t] += tmp;
        __syncthreads();
    }
    int incl = sc[t];
    if (i < N) cnt[i] = incl - val;
    if (t == 1023) bsum[blockIdx.x] = incl;
}

__global__ void k_scan2(int* __restrict__ bsum, int* __restrict__ offs, int nb, int N) {
    if (threadIdx.x == 0 && blockIdx.x == 0) {
        int run = 0;
        for (int i = 0; i < nb; ++i) { int tv = bsum[i]; bsum[i] = run; run += tv; }
        offs[N] = run;
    }
}

__global__ void k_scan3(int* __restrict__ offs, const int* __restrict__ bsum,
                        int* __restrict__ cursor, int N) {
    int i = blockIdx.x * 256 + threadIdx.x;
    if (i < N) {
        int o = offs[i] + bsum[i >> 10];
        offs[i] = o;
        cursor[i] = o;
    }
}

__global__ void k_scatter(const int* __restrict__ ei, int E, int N,
                          int* __restrict__ cursor, int* __restrict__ srcs,
                          int* __restrict__ dsts) {
    int i = blockIdx.x * 256 + threadIdx.x;
    int T = E + N;
    if (i >= T) return;
    int s_, d_;
    if (i < E) { s_ = ei[i]; d_ = ei[E + i]; }
    else       { s_ = i - E; d_ = i - E; }
    int p = atomicAdd(&cursor[d_], 1);
    srcs[p] = s_;
    dsts[p] = d_;
}

// ---------------- node transform: h=relu(xW_in+b); v=hW_lin; ps=h PsW; pd=h PdW --------
__global__ __launch_bounds__(256) void k_node(
    const float* __restrict__ x, const float* __restrict__ W_in, const float* __restrict__ b_in,
    const float* __restrict__ W_lin, const float* __restrict__ PsW, const float* __restrict__ PdW,
    float* __restrict__ v, float* __restrict__ ps, float* __restrict__ pd, int N)
{
    __shared__ float xsT[128][20];
    __shared__ float hsT[128][20];
    int t = threadIdx.x;
    int r0 = blockIdx.x * 16;

    for (int idx = t; idx < 16 * 128; idx += 256) {
        int r = idx >> 7, k = idx & 127;
        int row = r0 + r;
        xsT[k][r] = (row < N) ? x[row * 128 + k] : 0.f;
    }
    __syncthreads();

    int c = t & 127, rg = t >> 7;
    float acc[8];
    {
        float b = b_in[c];
        #pragma unroll
        for (int j = 0; j < 8; ++j) acc[j] = b;
        for (int k = 0; k < 128; ++k) {
            float w = W_in[k * 128 + c];
            const float4 xa = *(const float4*)&xsT[k][rg * 8];
            const float4 xb = *(const float4*)&xsT[k][rg * 8 + 4];
            acc[0] = fmaf(xa.x, w, acc[0]); acc[1] = fmaf(xa.y, w, acc[1]);
            acc[2] = fmaf(xa.z, w, acc[2]); acc[3] = fmaf(xa.w, w, acc[3]);
            acc[4] = fmaf(xb.x, w, acc[4]); acc[5] = fmaf(xb.y, w, acc[5]);
            acc[6] = fmaf(xb.z, w, acc[6]); acc[7] = fmaf(xb.w, w, acc[7]);
        }
        #pragma unroll
        for (int j = 0; j < 8; ++j) hsT[c][rg * 8 + j] = fmaxf(acc[j], 0.f);
    }
    __syncthreads();
    {
        #pragma unroll
        for (int j = 0; j < 8; ++j) acc[j] = 0.f;
        for (int k = 0; k < 128; ++k) {
            float w = W_lin[k * 128 + c];
            const float4 ha = *(const float4*)&hsT[k][rg * 8];
            const float4 hb = *(const float4*)&hsT[k][rg * 8 + 4];
            acc[0] = fmaf(ha.x, w, acc[0]); acc[1] = fmaf(ha.y, w, acc[1]);
            acc[2] = fmaf(ha.z, w, acc[2]); acc[3] = fmaf(ha.w, w, acc[3]);
            acc[4] = fmaf(hb.x, w, acc[4]); acc[5] = fmaf(hb.y, w, acc[5]);
            acc[6] = fmaf(hb.z, w, acc[6]); acc[7] = fmaf(hb.w, w, acc[7]);
        }
        #pragma unroll
        for (int j = 0; j < 8; ++j) {
            int row = r0 + rg * 8 + j;
            if (row < N) v[row * 128 + c] = acc[j];
        }
    }
    {
        int c2 = t & 63, g = t >> 6;
        float as[4], ad[4];
        #pragma unroll
        for (int j = 0; j < 4; ++j) { as[j] = 0.f; ad[j] = 0.f; }
        for (int k = 0; k < 128; ++k) {
            float wsv = PsW[k * 64 + c2];
            float wdv = PdW[k * 64 + c2];
            const float4 h4 = *(const float4*)&hsT[k][g * 4];
            as[0] = fmaf(h4.x, wsv, as[0]); as[1] = fmaf(h4.y, wsv, as[1]);
            as[2] = fmaf(h4.z, wsv, as[2]); as[3] = fmaf(h4.w, wsv, as[3]);
            ad[0] = fmaf(h4.x, wdv, ad[0]); ad[1] = fmaf(h4.y, wdv, ad[1]);
            ad[2] = fmaf(h4.z, wdv, ad[2]); ad[3] = fmaf(h4.w, wdv, ad[3]);
        }
        #pragma unroll
        for (int j = 0; j < 4; ++j) {
            int row = r0 + g * 4 + j;
            if (row < N) { ps[row * 64 + c2] = as[j]; pd[row * 64 + c2] = ad[j]; }
        }
    }
}

// ---------------- phase 1: per-edge MLPs via MFMA over 16-edge tiles ----------------
// Workgroup = 4 waves sharing fp16 weights in LDS. Per tile (16 edges):
//   GEMM1 ah = ph(16x64) @ M(64x64)       : 8  mfma 16x16x32
//   GEMM2 dl = ph(16x64) @ Wp2(64x128)    : 16 mfma
//   GEMM3 al = ahv(16x64) @ Wa2(64x128)   : 16 mfma
// A/B frags read k-consecutively with identical (lane>>4, elem) mapping (any HW
// k-permutation cancels). C/D: col=lane&15, row=(lane>>4)*4+j (m89-verified).
__global__ __launch_bounds__(256, 2) void k_edge(
    const float* __restrict__ v, const float* __restrict__ ps, const float* __restrict__ pd,
    const float4* __restrict__ pos4, const int* __restrict__ srcs, const int* __restrict__ dsts,
    const _Float16* __restrict__ Wcat,
    const float* __restrict__ Wp1, const float* __restrict__ bp1,
    const float* __restrict__ bias2, const float* __restrict__ bp2, const float* __restrict__ ba2,
    unsigned int* __restrict__ alpha_pk, unsigned int* __restrict__ u_pk,
    int Etot, int nTiles, int nWaves)
{
    __shared__ _Float16 WL[320 * 68];
    __shared__ _Float16 PH[4][16 * 68];
    __shared__ _Float16 AHV[4][16 * 68];
    int tid = threadIdx.x;
    {
        const unsigned int* g = (const unsigned int*)Wcat;
        unsigned int* s = (unsigned int*)WL;
        for (int i = tid; i < 320 * 68 / 2; i += 256) s[i] = g[i];
    }
    __syncthreads();

    int wid = tid >> 6, lane = tid & 63;
    int l15 = lane & 15, akg = lane >> 4;
    _Float16* ph  = PH[wid];
    _Float16* ahv = AHV[wid];

    float wp10 = Wp1[lane], wp11 = Wp1[64 + lane], wp12 = Wp1[128 + lane], bp1l = bp1[lane];
    float bias2_r[4], bp2_r[8], ba2_r[8];
    #pragma unroll
    for (int nt = 0; nt < 4; ++nt) bias2_r[nt] = bias2[nt * 16 + l15];
    #pragma unroll
    for (int nt = 0; nt < 8; ++nt) { bp2_r[nt] = bp2[nt * 16 + l15]; ba2_r[nt] = ba2[nt * 16 + l15]; }

    for (int t = blockIdx.x * 4 + wid; t < nTiles; t += nWaves) {
        int ebase = t * 16;
        int eidx = ebase + l15; if (eidx > Etot - 1) eidx = Etot - 1;
        int s16 = srcs[eidx], d16 = dsts[eidx];

        // pos_nn hidden: ph[e][h], lane = h
        #pragma unroll
        for (int ee = 0; ee < 16; ++ee) {
            int sj = __shfl(s16, ee), dj = __shfl(d16, ee);
            float4 pj = pos4[sj], pi = pos4[dj];
            float rx = pi.x - pj.x, ry = pi.y - pj.y, rz = pi.z - pj.z;
            float phv = fmaxf(fmaf(rx, wp10, fmaf(ry, wp11, fmaf(rz, wp12, bp1l))), 0.f);
            ph[ee * 68 + lane] = (_Float16)phv;
        }

        f16x8 A0 = ldfrag(&ph[l15 * 68 + akg * 8]);
        f16x8 A1 = ldfrag(&ph[l15 * 68 + 32 + akg * 8]);

        f32x4 acc1[4];
        #pragma unroll
        for (int nt = 0; nt < 4; ++nt) {
            const _Float16* br = &WL[(nt * 16 + l15) * 68];
            f16x8 B0 = ldfrag(br + akg * 8);
            f16x8 B1 = ldfrag(br + 32 + akg * 8);
            f32x4 a = {0.f, 0.f, 0.f, 0.f};
            a = __builtin_amdgcn_mfma_f32_16x16x32_f16(A0, B0, a, 0, 0, 0);
            a = __builtin_amdgcn_mfma_f32_16x16x32_f16(A1, B1, a, 0, 0, 0);
            acc1[nt] = a;
        }
        f32x4 acc2[8];
        #pragma unroll
        for (int nt = 0; nt < 8; ++nt) {
            const _Float16* br = &WL[(64 + nt * 16 + l15) * 68];
            f16x8 B0 = ldfrag(br + akg * 8);
            f16x8 B1 = ldfrag(br + 32 + akg * 8);
            f32x4 a = {0.f, 0.f, 0.f, 0.f};
            a = __builtin_amdgcn_mfma_f32_16x16x32_f16(A0, B0, a, 0, 0, 0);
            a = __builtin_amdgcn_mfma_f32_16x16x32_f16(A1, B1, a, 0, 0, 0);
            acc2[nt] = a;
        }

        int se[4], de[4];
        #pragma unroll
        for (int j = 0; j < 4; ++j) { se[j] = __shfl(s16, akg * 4 + j); de[j] = __shfl(d16, akg * 4 + j); }

        // base add + relu -> ahv (D layout: e=akg*4+j, l=nt*16+l15)
        #pragma unroll
        for (int nt = 0; nt < 4; ++nt) {
            #pragma unroll
            for (int j = 0; j < 4; ++j) {
                int l = nt * 16 + l15;
                float base = pd[(size_t)de[j] * 64 + l] - ps[(size_t)se[j] * 64 + l] + bias2_r[nt];
                float ahf = fmaxf(acc1[nt][j] + base, 0.f);
                ahv[(akg * 4 + j) * 68 + l] = (_Float16)ahf;
            }
        }

        f16x8 C0 = ldfrag(&ahv[l15 * 68 + akg * 8]);
        f16x8 C1 = ldfrag(&ahv[l15 * 68 + 32 + akg * 8]);
        f32x4 acc3[8];
        #pragma unroll
        for (int nt = 0; nt < 8; ++nt) {
            const _Float16* br = &WL[(192 + nt * 16 + l15) * 68];
            f16x8 B0 = ldfrag(br + akg * 8);
            f16x8 B1 = ldfrag(br + 32 + akg * 8);
            f32x4 a = {0.f, 0.f, 0.f, 0.f};
            a = __builtin_amdgcn_mfma_f32_16x16x32_f16(C0, B0, a, 0, 0, 0);
            a = __builtin_amdgcn_mfma_f32_16x16x32_f16(C1, B1, a, 0, 0, 0);
            acc3[nt] = a;
        }

        float uu[8][4];
        #pragma unroll
        for (int nt = 0; nt < 8; ++nt)
            #pragma unroll
            for (int j = 0; j < 4; ++j) {
                int c = nt * 16 + l15;
                uu[nt][j] = acc2[nt][j] + bp2_r[nt] + v[(size_t)se[j] * 128 + c];
            }

        // store packed fp16: word w in [0,64) holds channels (w, w+64)
        #pragma unroll
        for (int nt = 0; nt < 4; ++nt)
            #pragma unroll
            for (int j = 0; j < 4; ++j) {
                size_t er = (size_t)(ebase + akg * 4 + j);
                int w = nt * 16 + l15;
                unsigned int ap = pkrtz(acc3[nt][j] + ba2_r[nt], acc3[nt + 4][j] + ba2_r[nt + 4]);
                unsigned int up = pkrtz(uu[nt][j], uu[nt + 4][j]);
                alpha_pk[er * 64 + w] = ap;
                u_pk[er * 64 + w]     = up;
            }
    }
}

// ---------------- phase 2: per-node online softmax over CSR edge range ----------------
__global__ __launch_bounds__(256) void k_soft(
    const unsigned int* __restrict__ alpha_pk, const unsigned int* __restrict__ u_pk,
    const int* __restrict__ offs, float* __restrict__ out, int N, int nWaves)
{
    int wid = threadIdx.x >> 6, lane = threadIdx.x & 63;
    for (int node = blockIdx.x * 4 + wid; node < N; node += nWaves) {
        int beg = offs[node], end = offs[node + 1];
        float m0 = -__builtin_inff(), m1 = m0, s0 = 0.f, s1 = 0.f, a0 = 0.f, a1 = 0.f;
        unsigned int apkC = alpha_pk[(size_t)beg * 64 + lane];
        unsigned int upkC = u_pk[(size_t)beg * 64 + lane];
        for (int e = beg; e < end; ++e) {
            int en = (e + 1 < end) ? e + 1 : e;
            unsigned int apkN = alpha_pk[(size_t)en * 64 + lane];
            unsigned int upkN = u_pk[(size_t)en * 64 + lane];
            h2_t ah = __builtin_bit_cast(h2_t, apkC);
            h2_t uh = __builtin_bit_cast(h2_t, upkC);
            float al0 = (float)ah.x, al1 = (float)ah.y;
            float u0  = (float)uh.x, u1  = (float)uh.y;
            float nm0 = fmaxf(m0, al0);
            float sc0 = __expf(m0 - nm0), p0 = __expf(al0 - nm0);
            s0 = fmaf(s0, sc0, p0); a0 = fmaf(a0, sc0, p0 * u0); m0 = nm0;
            float nm1 = fmaxf(m1, al1);
            float sc1 = __expf(m1 - nm1), p1 = __expf(al1 - nm1);
            s1 = fmaf(s1, sc1, p1); a1 = fmaf(a1, sc1, p1 * u1); m1 = nm1;
            apkC = apkN; upkC = upkN;
        }
        out[(size_t)node * 128 + lane]      = a0 / (s0 + 1e-16f);
        out[(size_t)node * 128 + 64 + lane] = a1 / (s1 + 1e-16f);
    }
}

// ---------------- fallback: round-3 fused edge aggregation (if ws too small) --------
__global__ __launch_bounds__(64, 2) void k_agg(
    const float* __restrict__ v, const float* __restrict__ ps, const float* __restrict__ pd,
    const float4* __restrict__ pos4, const int* __restrict__ offs, const int* __restrict__ srcs,
    const float* __restrict__ Wp1, const float* __restrict__ bp1,
    const float* __restrict__ bias2, const float* __restrict__ bp2, const float* __restrict__ ba2,
    const unsigned int* __restrict__ Mpk, const unsigned int* __restrict__ Wp2pk,
    const unsigned int* __restrict__ Wa2pk,
    float* __restrict__ out, int N, int totWaves)
{
    __shared__ __align__(16) unsigned int wlh[64];
    int lane = threadIdx.x;
    int gw = blockIdx.x;
    int half = gw & 1;
    int cc = (half << 6) + lane;

    unsigned int mcol[32], wp2c[32], wa2c[32];
    #pragma unroll
    for (int t = 0; t < 32; ++t) {
        mcol[t] = Mpk[t * 64 + lane];
        wp2c[t] = Wp2pk[t * 128 + cc];
        wa2c[t] = Wa2pk[t * 128 + cc];
    }
    float wp10 = Wp1[lane], wp11 = Wp1[64 + lane], wp12 = Wp1[128 + lane];
    float bp1l = bp1[lane], bias2l = bias2[lane];
    float ba2c = ba2[cc], bp2c = bp2[cc];

    _Float16* wlph = (_Float16*)wlh;
    const uint4* wl4 = (const uint4*)wlh;

    int nodeStride = totWaves >> 1;
    for (int node = (gw >> 1); node < N; node += nodeStride) {
        int beg = offs[node], end = offs[node + 1];
        float pdl = pd[node * 64 + lane];
        float4 pi = pos4[node];
        float mM = -__builtin_inff(), sS = 0.f, aA = 0.f;

        int   srcC = srcs[beg];
        float pslC = ps[srcC * 64 + lane];
        float uvC  = v[srcC * 128 + cc];
        float4 pjC = pos4[srcC];

        for (int e = beg; e < end; ++e) {
            int en = (e + 1 < end) ? (e + 1) : e;
            int   srcN = srcs[en];
            float pslN = ps[srcN * 64 + lane];
            float uvN  = v[srcN * 128 + cc];
            float4 pjN = pos4[srcN];

            float rx = pi.x - pjC.x, ry = pi.y - pjC.y, rz = pi.z - pjC.z;
            float phv = fmaxf(fmaf(rx, wp10, fmaf(ry, wp11, fmaf(rz, wp12, bp1l))), 0.f);
            wlph[lane] = (_Float16)phv;

            float ahp0 = (pdl - pslC) + bias2l, ahp1 = 0.f;
            float dlt0 = bp2c, dlt1 = 0.f;
            #pragma unroll
            for (int j = 0; j < 8; ++j) {
                uint4 q = wl4[j];
                ahp0 = fdot2f(q.x, mcol[4*j+0], ahp0);
                dlt0 = fdot2f(q.x, wp2c[4*j+0], dlt0);
                ahp1 = fdot2f(q.y, mcol[4*j+1], ahp1);
                dlt1 = fdot2f(q.y, wp2c[4*j+1], dlt1);
                ahp0 = fdot2f(q.z, mcol[4*j+2], ahp0);
                dlt0 = fdot2f(q.z, wp2c[4*j+2], dlt0);
                ahp1 = fdot2f(q.w, mcol[4*j+3], ahp1);
                dlt1 = fdot2f(q.w, wp2c[4*j+3], dlt1);
            }
            float ahv = fmaxf(ahp0 + ahp1, 0.f);
            float dlt = dlt0 + dlt1;
            wlph[64 + lane] = (_Float16)ahv;

            float al0 = ba2c, al1 = 0.f;
            #pragma unroll
            for (int j = 8; j < 16; ++j) {
                uint4 q = wl4[j];
                al0 = fdot2f(q.x, wa2c[4*(j-8)+0], al0);
                al1 = fdot2f(q.y, wa2c[4*(j-8)+1], al1);
                al0 = fdot2f(q.z, wa2c[4*(j-8)+2], al0);
                al1 = fdot2f(q.w, wa2c[4*(j-8)+3], al1);
            }
            float al = al0 + al1;

            float u  = uvC + dlt;
            float nm = fmaxf(mM, al);
            float scl = __expf(mM - nm);
            float pv  = __expf(al - nm);
            sS = fmaf(sS, scl, pv);
            aA = fmaf(aA, scl, pv * u);
            mM = nm;

            srcC = srcN; pslC = pslN; uvC = uvN; pjC = pjN;
        }
        out[node * 128 + cc] = aA / (sS + 1e-16f);
    }
}

// ---------------- lin_out + residual (in-place on d_out) ----------------
__global__ __launch_bounds__(256) void k_out(
    const float* __restrict__ x, const float* __restrict__ W_out, const float* __restrict__ b_out,
    float* __restrict__ out, int N)
{
    __shared__ float csT[128][20];
    int t = threadIdx.x;
    int r0 = blockIdx.x * 16;

    for (int idx = t; idx < 16 * 128; idx += 256) {
        int r = idx >> 7, k = idx & 127;
        int row = r0 + r;
        csT[k][r] = (row < N) ? out[row * 128 + k] : 0.f;
    }
    __syncthreads();

    int c = t & 127, rg = t >> 7;
    float acc[8];
    float b = b_out[c];
    #pragma unroll
    for (int j = 0; j < 8; ++j) acc[j] = b;
    for (int k = 0; k < 128; ++k) {
        float w = W_out[k * 128 + c];
        const float4 ca = *(const float4*)&csT[k][rg * 8];
        const float4 cb = *(const float4*)&csT[k][rg * 8 + 4];
        acc[0] = fmaf(ca.x, w, acc[0]); acc[1] = fmaf(ca.y, w, acc[1]);
        acc[2] = fmaf(ca.z, w, acc[2]); acc[3] = fmaf(ca.w, w, acc[3]);
        acc[4] = fmaf(cb.x, w, acc[4]); acc[5] = fmaf(cb.y, w, acc[5]);
        acc[6] = fmaf(cb.z, w, acc[6]); acc[7] = fmaf(cb.w, w, acc[7]);
    }
    #pragma unroll
    for (int j = 0; j < 8; ++j) {
        int row = r0 + rg * 8 + j;
        if (row < N) out[row * 128 + c] = fmaxf(acc[j], 0.f) + x[row * 128 + c];
    }
}

extern "C" void kernel_launch(void* const* d_in, const int* in_sizes, int n_in,
                              void* d_out, int out_size, void* d_ws, size_t ws_size,
                              hipStream_t stream)
{
    const float* x     = (const float*)d_in[0];
    const float* pos   = (const float*)d_in[1];
    const int*   ei    = (const int*)d_in[2];
    const float* W_in  = (const float*)d_in[3];
    const float* b_in  = (const float*)d_in[4];
    const float* W_out = (const float*)d_in[5];
    const float* b_out = (const float*)d_in[6];
    const float* W_lin = (const float*)d_in[7];
    const float* W_src = (const float*)d_in[8];
    const float* W_dst = (const float*)d_in[9];
    const float* Wp1   = (const float*)d_in[10];
    const float* bp1   = (const float*)d_in[11];
    const float* Wp2   = (const float*)d_in[12];
    const float* bp2   = (const float*)d_in[13];
    const float* Wa1   = (const float*)d_in[14];
    const float* ba1   = (const float*)d_in[15];
    const float* Wa2   = (const float*)d_in[16];
    const float* ba2   = (const float*)d_in[17];

    int N = in_sizes[0] / 128;
    int E = in_sizes[2] / 2;
    int T = E + N;
    int nTiles = (T + 15) / 16;
    float* out = (float*)d_out;

    char* w = (char*)d_ws;
    auto alloc = [&](size_t bytes) -> char* {
        char* p = w;
        w += (bytes + 255) & ~(size_t)255;
        return p;
    };
    float* v_    = (float*)alloc((size_t)N * 128 * 4);
    float* ps_   = (float*)alloc((size_t)N * 64 * 4);
    float* pd_   = (float*)alloc((size_t)N * 64 * 4);
    float4* pos4 = (float4*)alloc((size_t)N * 16);
    float* PsW   = (float*)alloc(8192 * 4);
    float* PdW   = (float*)alloc(8192 * 4);
    unsigned int* Mpk   = (unsigned int*)alloc(2048 * 4);
    unsigned int* Wp2pk = (unsigned int*)alloc(4096 * 4);
    unsigned int* Wa2pk = (unsigned int*)alloc(4096 * 4);
    float* bias2 = (float*)alloc(64 * 4);
    _Float16* Wcat = (_Float16*)alloc(320 * 68 * 2);
    int*   offs  = (int*)alloc((size_t)(N + 1) * 4);
    int*   cursor= (int*)alloc((size_t)N * 4);
    int*   bsum  = (int*)alloc(256 * 4);
    int*   srcs  = (int*)alloc((size_t)T * 4);
    int*   dsts  = (int*)alloc((size_t)T * 4);
    unsigned int* alpha_pk = (unsigned int*)alloc((size_t)nTiles * 16 * 64 * 4);
    unsigned int* u_pk     = (unsigned int*)alloc((size_t)nTiles * 16 * 64 * 4);
    size_t need = (size_t)(w - (char*)d_ws);
    bool big = (need <= ws_size);

    k_pre<<<dim3((26688 + 320*68 + 255) / 256), dim3(256), 0, stream>>>(
        W_src, W_dst, Wa1, ba1, Wp2, bp2, Wa2, PsW, PdW, Mpk, Wp2pk, Wa2pk, bias2, Wcat);
    k_zero<<<dim3((N + 1 + 255) / 256), dim3(256), 0, stream>>>(offs, N + 1);
    k_count<<<dim3((T + 255) / 256), dim3(256), 0, stream>>>(ei, E, N, offs);
    k_pos4<<<dim3((N + 255) / 256), dim3(256), 0, stream>>>(pos, pos4, N);
    int nb = (N + 1023) / 1024;
    k_scan1<<<dim3(nb), dim3(1024), 0, stream>>>(offs, bsum, N);
    k_scan2<<<dim3(1), dim3(64), 0, stream>>>(bsum, offs, nb, N);
    k_scan3<<<dim3((N + 255) / 256), dim3(256), 0, stream>>>(offs, bsum, cursor, N);
    k_scatter<<<dim3((T + 255) / 256), dim3(256), 0, stream>>>(ei, E, N, cursor, srcs, dsts);
    k_node<<<dim3((N + 15) / 16), dim3(256), 0, stream>>>(x, W_in, b_in, W_lin, PsW, PdW, v_, ps_, pd_, N);

    if (big) {
        int nWaves = 8192;
        k_edge<<<dim3(2048), dim3(256), 0, stream>>>(v_, ps_, pd_, pos4, srcs, dsts, Wcat,
                                                     Wp1, bp1, bias2, bp2, ba2,
                                                     alpha_pk, u_pk, T, nTiles, nWaves);
        k_soft<<<dim3(2048), dim3(256), 0, stream>>>(alpha_pk, u_pk, offs, out, N, nWaves);
    } else {
        int totWaves = 8192;
        k_agg<<<dim3(totWaves), dim3(64), 0, stream>>>(v_, ps_, pd_, pos4, offs, srcs,
                                                       Wp1, bp1, bias2, bp2, ba2,
                                                       Mpk, Wp2pk, Wa2pk,
                                                       out, N, totWaves);
    }
    k_out<<<dim3((N + 15) / 16), dim3(256), 0, stream>>>(x, W_out, b_out, out, N);
}